// Round 1
// baseline (477.827 us; speedup 1.0000x reference)
//
#include <hip/hip_runtime.h>
#include <hip/hip_bf16.h>
#include <cstdint>
#include <cstddef>

typedef unsigned short u16;
typedef __bf16 bf16x8 __attribute__((ext_vector_type(8)));
typedef float f32x4 __attribute__((ext_vector_type(4)));

#define D_MODEL 1024
#define D_FF    4096
#define BATCH   2
#define SEQ     2048
#define NH      16
#define HD      64
#define ROWS    (BATCH*SEQ)   // 4096

// ---------- helpers ----------
__device__ __forceinline__ u16 f2bf(float f) {
    union { float f; uint32_t u; } v; v.f = f;
    uint32_t u = v.u;
    u += 0x7FFF + ((u >> 16) & 1);   // RNE
    return (u16)(u >> 16);
}

__device__ __forceinline__ bf16x8 ldg8(const u16* p) {
    return *reinterpret_cast<const bf16x8*>(p);
}

__device__ __forceinline__ f32x4 mfma16(bf16x8 a, bf16x8 b, f32x4 c) {
    return __builtin_amdgcn_mfma_f32_16x16x32_bf16(a, b, c, 0, 0, 0);
}

__device__ __forceinline__ void gld_lds16(const void* g, void* l) {
    __builtin_amdgcn_global_load_lds(
        (const __attribute__((address_space(1))) void*)g,
        (__attribute__((address_space(3))) void*)l, 16, 0, 0);
}

struct alignas(8) U16x4 { u16 x, y, z, w; };

// ---------- f32 -> bf16 convert ----------
__global__ void cvt_bf16(const float* __restrict__ in, u16* __restrict__ out, int n) {
    int i = (blockIdx.x * 256 + threadIdx.x) * 4;
    if (i >= n) return;
    float4 f = *reinterpret_cast<const float4*>(in + i);
    U16x4 o{ f2bf(f.x), f2bf(f.y), f2bf(f.z), f2bf(f.w) };
    *reinterpret_cast<U16x4*>(out + i) = o;
}

// ---------- LayerNorm (f32 in, bf16 out) ----------
__global__ __launch_bounds__(256) void ln_bf16(
    const float* __restrict__ x, const float* __restrict__ g,
    const float* __restrict__ b, u16* __restrict__ out)
{
    int row = blockIdx.x;
    const float* xr = x + (size_t)row * D_MODEL;
    int t = threadIdx.x;
    float4 v = *reinterpret_cast<const float4*>(xr + t * 4);
    float s = v.x + v.y + v.z + v.w;
    float q = v.x*v.x + v.y*v.y + v.z*v.z + v.w*v.w;
    #pragma unroll
    for (int off = 1; off < 64; off <<= 1) {
        s += __shfl_xor(s, off);
        q += __shfl_xor(q, off);
    }
    __shared__ float red[8];
    if ((t & 63) == 0) { red[(t >> 6) * 2] = s; red[(t >> 6) * 2 + 1] = q; }
    __syncthreads();
    float sum = red[0] + red[2] + red[4] + red[6];
    float sq  = red[1] + red[3] + red[5] + red[7];
    float mu  = sum * (1.0f / D_MODEL);
    float var = sq * (1.0f / D_MODEL) - mu * mu;
    float rstd = rsqrtf(var + 1e-6f);
    float4 gg = *reinterpret_cast<const float4*>(g + t * 4);
    float4 bb = *reinterpret_cast<const float4*>(b + t * 4);
    U16x4 o{ f2bf((v.x - mu) * rstd * gg.x + bb.x),
             f2bf((v.y - mu) * rstd * gg.y + bb.y),
             f2bf((v.z - mu) * rstd * gg.z + bb.z),
             f2bf((v.w - mu) * rstd * gg.w + bb.w) };
    *reinterpret_cast<U16x4*>(out + (size_t)row * D_MODEL + t * 4) = o;
}

// ---------- GEMM: C[M,N] = A[M,K](bf16) @ W[N,K]^T(bf16) + bias, epilogues ----------
#define EPI_BF16   0
#define EPI_RESF32 1
#define EPI_GELU   2

template<int EPI>
__global__ __launch_bounds__(256, 2) void gemm_bt(
    const u16* __restrict__ A, const u16* __restrict__ B,
    const float* __restrict__ bias, const float* __restrict__ res,
    u16* __restrict__ outb, float* __restrict__ outf,
    int M, int N, int K)
{
    __shared__ u16 As[2][128 * 64];
    __shared__ u16 Bs[2][128 * 64];
    const int t = threadIdx.x;
    const int lane = t & 63;
    const int w = t >> 6;
    const int lr = lane & 15, lg = lane >> 4;
    const int wrr = (w >> 1) * 64, wcc = (w & 1) * 64;
    const int brow = blockIdx.y * 128, bcol = blockIdx.x * 128;
    const u16* Ag = A + (size_t)brow * K;
    const u16* Bg = B + (size_t)bcol * K;

    f32x4 acc[4][4] = {};

    const int NT = K >> 6;

    auto stage = [&](int buf, int kt) {
        const u16* ga = Ag + kt * 64;
        const u16* gb = Bg + kt * 64;
        u16* la = As[buf];
        u16* lb = Bs[buf];
        #pragma unroll
        for (int c = 0; c < 4; ++c) {
            int f = c * 256 + t;
            int row = f >> 3, slot = f & 7;
            int sg = slot ^ (row & 7);          // inverse-swizzled global source
            gld_lds16(ga + (size_t)row * K + sg * 8, la + f * 8);
            gld_lds16(gb + (size_t)row * K + sg * 8, lb + f * 8);
        }
    };

    auto compute = [&](int buf) {
        const u16* la = As[buf];
        const u16* lb = Bs[buf];
        bf16x8 af[4][2];
        #pragma unroll
        for (int mi = 0; mi < 4; ++mi) {
            int row = wrr + mi * 16 + lr;
            int base = row * 64;
            af[mi][0] = *reinterpret_cast<const bf16x8*>(la + base + ((0 + lg) ^ (row & 7)) * 8);
            af[mi][1] = *reinterpret_cast<const bf16x8*>(la + base + ((4 + lg) ^ (row & 7)) * 8);
        }
        #pragma unroll
        for (int ni = 0; ni < 4; ++ni) {
            int row = wcc + ni * 16 + lr;
            int base = row * 64;
            bf16x8 b0 = *reinterpret_cast<const bf16x8*>(lb + base + ((0 + lg) ^ (row & 7)) * 8);
            bf16x8 b1 = *reinterpret_cast<const bf16x8*>(lb + base + ((4 + lg) ^ (row & 7)) * 8);
            #pragma unroll
            for (int mi = 0; mi < 4; ++mi) {
                acc[mi][ni] = mfma16(af[mi][0], b0, acc[mi][ni]);
                acc[mi][ni] = mfma16(af[mi][1], b1, acc[mi][ni]);
            }
        }
    };

    stage(0, 0);
    __syncthreads();
    for (int kt = 0; kt < NT; ++kt) {
        if (kt + 1 < NT) stage((kt + 1) & 1, kt + 1);
        compute(kt & 1);
        __syncthreads();
    }

    // epilogue
    #pragma unroll
    for (int mi = 0; mi < 4; ++mi) {
        int r0 = brow + wrr + mi * 16 + lg * 4;
        #pragma unroll
        for (int ni = 0; ni < 4; ++ni) {
            int c = bcol + wcc + ni * 16 + lr;
            float bv = bias[c];
            #pragma unroll
            for (int j = 0; j < 4; ++j) {
                float v = acc[mi][ni][j] + bv;
                size_t idx = (size_t)(r0 + j) * N + c;
                if constexpr (EPI == EPI_GELU) {
                    v = 0.5f * v * (1.0f + erff(v * 0.70710678118f));
                    outb[idx] = f2bf(v);
                } else if constexpr (EPI == EPI_RESF32) {
                    outf[idx] = v + res[idx];
                } else {
                    outb[idx] = f2bf(v);
                }
            }
        }
    }
}

// ---------- causal flash attention: 1 wave, 16 q-rows, KV tiles of 32 ----------
__global__ __launch_bounds__(64) void attn(
    const u16* __restrict__ Q, const u16* __restrict__ K,
    const u16* __restrict__ V, u16* __restrict__ O)
{
    const int bid = blockIdx.x;
    const int qt = bid & 127;            // S/16
    const int h  = (bid >> 7) & 15;
    const int b  = bid >> 11;
    const int l  = threadIdx.x;
    const int lr = l & 15, lg = l >> 4;

    __shared__ u16 P_lds[16 * 40];       // padded stride 40 (80B) -> conflict-free b128
    __shared__ u16 Vt[64 * 40];          // [d][kv], padded

    const size_t qbase = ((size_t)(b * SEQ + qt * 16 + lr)) * D_MODEL + h * HD;
    bf16x8 qf0 = ldg8(Q + qbase + lg * 8);
    bf16x8 qf1 = ldg8(Q + qbase + 32 + lg * 8);

    f32x4 o0 = {}, o1 = {}, o2 = {}, o3 = {};
    float mrow[4] = { -1e30f, -1e30f, -1e30f, -1e30f };
    float lrow[4] = { 0.f, 0.f, 0.f, 0.f };

    const int ntiles = (qt * 16 + 15) / 32 + 1;
    const u16* Kb = K + ((size_t)b * SEQ) * D_MODEL + h * HD;
    const u16* Vb = V + ((size_t)b * SEQ) * D_MODEL + h * HD;

    for (int tt = 0; tt < ntiles; ++tt) {
        int kv0 = tt * 32;
        // QK^T: two 16x16 n-tiles
        f32x4 s0 = {}, s1 = {};
        {
            const u16* kr  = Kb + (size_t)(kv0 + lr) * D_MODEL + lg * 8;
            const u16* kr2 = kr + (size_t)16 * D_MODEL;
            s0 = mfma16(qf0, ldg8(kr), s0);
            s0 = mfma16(qf1, ldg8(kr + 32), s0);
            s1 = mfma16(qf0, ldg8(kr2), s1);
            s1 = mfma16(qf1, ldg8(kr2 + 32), s1);
        }
        // stage V transposed into LDS: Vt[d][kv]
        {
            const u16* vr = Vb + (size_t)(kv0 + (l & 31)) * D_MODEL;
            #pragma unroll
            for (int c = 0; c < 4; ++c) {
                int dc = c * 2 + (l >> 5);   // 0..7 (8-col chunk)
                bf16x8 vv = ldg8(vr + dc * 8);
                #pragma unroll
                for (int i2 = 0; i2 < 8; ++i2)
                    Vt[(dc * 8 + i2) * 40 + (l & 31)] = ((const u16*)&vv)[i2];
            }
        }
        // softmax (online), D-layout: row = lg*4+j, col = lr (+16 for s1)
        bool diag = (kv0 + 31 > qt * 16);
        #pragma unroll
        for (int j = 0; j < 4; ++j) {
            float a0 = s0[j] * 0.125f, a1 = s1[j] * 0.125f;
            if (diag) {
                int qi = qt * 16 + lg * 4 + j;
                if (kv0 + lr > qi)      a0 = -1e9f;
                if (kv0 + 16 + lr > qi) a1 = -1e9f;
            }
            float mm = fmaxf(a0, a1);
            mm = fmaxf(mm, __shfl_xor(mm, 1));
            mm = fmaxf(mm, __shfl_xor(mm, 2));
            mm = fmaxf(mm, __shfl_xor(mm, 4));
            mm = fmaxf(mm, __shfl_xor(mm, 8));
            float mn = fmaxf(mrow[j], mm);
            float corr = __expf(mrow[j] - mn);
            mrow[j] = mn;
            float p0 = __expf(a0 - mn), p1 = __expf(a1 - mn);
            float pp = p0 + p1;
            pp += __shfl_xor(pp, 1);
            pp += __shfl_xor(pp, 2);
            pp += __shfl_xor(pp, 4);
            pp += __shfl_xor(pp, 8);
            lrow[j] = lrow[j] * corr + pp;
            o0[j] *= corr; o1[j] *= corr; o2[j] *= corr; o3[j] *= corr;
            P_lds[(lg * 4 + j) * 40 + lr]      = f2bf(p0);
            P_lds[(lg * 4 + j) * 40 + 16 + lr] = f2bf(p1);
        }
        __syncthreads();
        // PV: P[16x32] @ V[32x64]
        bf16x8 pf = *reinterpret_cast<const bf16x8*>(&P_lds[lr * 40 + lg * 8]);
        o0 = mfma16(pf, *reinterpret_cast<const bf16x8*>(&Vt[(0  + lr) * 40 + lg * 8]), o0);
        o1 = mfma16(pf, *reinterpret_cast<const bf16x8*>(&Vt[(16 + lr) * 40 + lg * 8]), o1);
        o2 = mfma16(pf, *reinterpret_cast<const bf16x8*>(&Vt[(32 + lr) * 40 + lg * 8]), o2);
        o3 = mfma16(pf, *reinterpret_cast<const bf16x8*>(&Vt[(48 + lr) * 40 + lg * 8]), o3);
        __syncthreads();
    }

    #pragma unroll
    for (int j = 0; j < 4; ++j) {
        float inv = 1.0f / lrow[j];
        size_t ob = ((size_t)(b * SEQ + qt * 16 + lg * 4 + j)) * D_MODEL + h * HD + lr;
        O[ob]      = f2bf(o0[j] * inv);
        O[ob + 16] = f2bf(o1[j] * inv);
        O[ob + 32] = f2bf(o2[j] * inv);
        O[ob + 48] = f2bf(o3[j] * inv);
    }
}

// ---------- launch ----------
extern "C" void kernel_launch(void* const* d_in, const int* in_sizes, int n_in,
                              void* d_out, int out_size, void* d_ws, size_t ws_size,
                              hipStream_t stream)
{
    (void)in_sizes; (void)n_in; (void)out_size; (void)ws_size;
    const float* x   = (const float*)d_in[0];
    const float* Wq  = (const float*)d_in[2];
    const float* bq  = (const float*)d_in[3];
    const float* Wk  = (const float*)d_in[4];
    const float* bk  = (const float*)d_in[5];
    const float* Wv  = (const float*)d_in[6];
    const float* bv  = (const float*)d_in[7];
    const float* Wo  = (const float*)d_in[8];
    const float* bo  = (const float*)d_in[9];
    const float* g1  = (const float*)d_in[10];
    const float* be1 = (const float*)d_in[11];
    const float* g2  = (const float*)d_in[12];
    const float* be2 = (const float*)d_in[13];
    const float* W1  = (const float*)d_in[14];
    const float* b1  = (const float*)d_in[15];
    const float* W2  = (const float*)d_in[16];
    const float* b2  = (const float*)d_in[17];
    float* out = (float*)d_out;

    const int MM  = 1 << 20;   // 1M elems
    u16* Wq_b = (u16*)d_ws;
    u16* Wk_b = Wq_b + MM;
    u16* Wv_b = Wk_b + MM;
    u16* Wo_b = Wv_b + MM;
    u16* W1_b = Wo_b + MM;          // 4M
    u16* W2_b = W1_b + 4 * MM;      // 4M
    u16* hbuf = W2_b + 4 * MM;      // 4M
    u16* Qb   = hbuf + 4 * MM;
    u16* Kb   = Qb + 4 * MM;
    u16* Vb   = Kb + 4 * MM;
    u16* ctx  = Vb + 4 * MM;
    u16* ffn1 = ctx + 4 * MM;       // 16M
    float* x2 = (float*)(ffn1 + 16 * MM);

    // weight converts
    cvt_bf16<<<MM / 1024, 256, 0, stream>>>(Wq, Wq_b, MM);
    cvt_bf16<<<MM / 1024, 256, 0, stream>>>(Wk, Wk_b, MM);
    cvt_bf16<<<MM / 1024, 256, 0, stream>>>(Wv, Wv_b, MM);
    cvt_bf16<<<MM / 1024, 256, 0, stream>>>(Wo, Wo_b, MM);
    cvt_bf16<<<4 * MM / 1024, 256, 0, stream>>>(W1, W1_b, 4 * MM);
    cvt_bf16<<<4 * MM / 1024, 256, 0, stream>>>(W2, W2_b, 4 * MM);

    // LN1
    ln_bf16<<<ROWS, 256, 0, stream>>>(x, g1, be1, hbuf);

    dim3 blk(256);
    dim3 gq(D_MODEL / 128, ROWS / 128);       // (8, 32)
    gemm_bt<EPI_BF16><<<gq, blk, 0, stream>>>(hbuf, Wq_b, bq, nullptr, Qb, nullptr, ROWS, D_MODEL, D_MODEL);
    gemm_bt<EPI_BF16><<<gq, blk, 0, stream>>>(hbuf, Wk_b, bk, nullptr, Kb, nullptr, ROWS, D_MODEL, D_MODEL);
    gemm_bt<EPI_BF16><<<gq, blk, 0, stream>>>(hbuf, Wv_b, bv, nullptr, Vb, nullptr, ROWS, D_MODEL, D_MODEL);

    attn<<<BATCH * NH * (SEQ / 16), 64, 0, stream>>>(Qb, Kb, Vb, ctx);

    gemm_bt<EPI_RESF32><<<gq, blk, 0, stream>>>(ctx, Wo_b, bo, x, nullptr, x2, ROWS, D_MODEL, D_MODEL);

    // LN2
    ln_bf16<<<ROWS, 256, 0, stream>>>(x2, g2, be2, hbuf);

    dim3 gf1(D_FF / 128, ROWS / 128);         // (32, 32)
    gemm_bt<EPI_GELU><<<gf1, blk, 0, stream>>>(hbuf, W1_b, b1, nullptr, ffn1, nullptr, ROWS, D_FF, D_MODEL);

    gemm_bt<EPI_RESF32><<<gq, blk, 0, stream>>>(ffn1, W2_b, b2, x2, nullptr, out, ROWS, D_MODEL, D_FF);
}

// Round 2
// 367.313 us; speedup vs baseline: 1.3009x; 1.3009x over previous
//
#include <hip/hip_runtime.h>
#include <hip/hip_bf16.h>
#include <cstdint>
#include <cstddef>

typedef unsigned short u16;
typedef __bf16 bf16x8 __attribute__((ext_vector_type(8)));
typedef float f32x4 __attribute__((ext_vector_type(4)));

#define D_MODEL 1024
#define D_FF    4096
#define BATCH   2
#define SEQ     2048
#define NH      16
#define HD      64
#define ROWS    (BATCH*SEQ)   // 4096
#define QKVS    3072          // packed QKV row stride

// ---------- helpers ----------
__device__ __forceinline__ u16 f2bf(float f) {
    union { float f; uint32_t u; } v; v.f = f;
    uint32_t u = v.u;
    u += 0x7FFF + ((u >> 16) & 1);   // RNE
    return (u16)(u >> 16);
}

__device__ __forceinline__ bf16x8 ldg8(const u16* p) {
    return *reinterpret_cast<const bf16x8*>(p);
}

__device__ __forceinline__ f32x4 mfma16(bf16x8 a, bf16x8 b, f32x4 c) {
    return __builtin_amdgcn_mfma_f32_16x16x32_bf16(a, b, c, 0, 0, 0);
}

__device__ __forceinline__ void gld_lds16(const void* g, void* l) {
    __builtin_amdgcn_global_load_lds(
        (const __attribute__((address_space(1))) void*)g,
        (__attribute__((address_space(3))) void*)l, 16, 0, 0);
}

struct alignas(8) U16x4 { u16 x, y, z, w; };

// ---------- f32 -> bf16 convert ----------
__global__ void cvt_bf16(const float* __restrict__ in, u16* __restrict__ out, int n) {
    int i = (blockIdx.x * 256 + threadIdx.x) * 4;
    if (i >= n) return;
    float4 f = *reinterpret_cast<const float4*>(in + i);
    U16x4 o{ f2bf(f.x), f2bf(f.y), f2bf(f.z), f2bf(f.w) };
    *reinterpret_cast<U16x4*>(out + i) = o;
}

// ---------- LayerNorm (f32 in, bf16 out) ----------
__global__ __launch_bounds__(256) void ln_bf16(
    const float* __restrict__ x, const float* __restrict__ g,
    const float* __restrict__ b, u16* __restrict__ out)
{
    int row = blockIdx.x;
    const float* xr = x + (size_t)row * D_MODEL;
    int t = threadIdx.x;
    float4 v = *reinterpret_cast<const float4*>(xr + t * 4);
    float s = v.x + v.y + v.z + v.w;
    float q = v.x*v.x + v.y*v.y + v.z*v.z + v.w*v.w;
    #pragma unroll
    for (int off = 1; off < 64; off <<= 1) {
        s += __shfl_xor(s, off);
        q += __shfl_xor(q, off);
    }
    __shared__ float red[8];
    if ((t & 63) == 0) { red[(t >> 6) * 2] = s; red[(t >> 6) * 2 + 1] = q; }
    __syncthreads();
    float sum = red[0] + red[2] + red[4] + red[6];
    float sq  = red[1] + red[3] + red[5] + red[7];
    float mu  = sum * (1.0f / D_MODEL);
    float var = sq * (1.0f / D_MODEL) - mu * mu;
    float rstd = rsqrtf(var + 1e-6f);
    float4 gg = *reinterpret_cast<const float4*>(g + t * 4);
    float4 bb = *reinterpret_cast<const float4*>(b + t * 4);
    U16x4 o{ f2bf((v.x - mu) * rstd * gg.x + bb.x),
             f2bf((v.y - mu) * rstd * gg.y + bb.y),
             f2bf((v.z - mu) * rstd * gg.z + bb.z),
             f2bf((v.w - mu) * rstd * gg.w + bb.w) };
    *reinterpret_cast<U16x4*>(out + (size_t)row * D_MODEL + t * 4) = o;
}

// ---------- GEMM: C[M,N] = A[M,K](bf16) @ W[N,K]^T(bf16) + bias, epilogues ----------
#define EPI_BF16   0
#define EPI_RESF32 1
#define EPI_GELU   2

template<int EPI>
__global__ __launch_bounds__(256, 2) void gemm_bt(
    const u16* __restrict__ A, const u16* __restrict__ B,
    const float* __restrict__ bias, const float* __restrict__ res,
    u16* __restrict__ outb, float* __restrict__ outf,
    int M, int N, int K)
{
    __shared__ u16 As[2][128 * 64];
    __shared__ u16 Bs[2][128 * 64];
    const int t = threadIdx.x;
    const int lane = t & 63;
    const int w = t >> 6;
    const int lr = lane & 15, lg = lane >> 4;
    const int wrr = (w >> 1) * 64, wcc = (w & 1) * 64;
    const int brow = blockIdx.y * 128, bcol = blockIdx.x * 128;
    const u16* Ag = A + (size_t)brow * K;
    const u16* Bg = B + (size_t)bcol * K;

    f32x4 acc[4][4] = {};

    const int NT = K >> 6;

    auto stage = [&](int buf, int kt) {
        const u16* ga = Ag + kt * 64;
        const u16* gb = Bg + kt * 64;
        u16* la = As[buf];
        u16* lb = Bs[buf];
        #pragma unroll
        for (int c = 0; c < 4; ++c) {
            int f = c * 256 + t;
            int row = f >> 3, slot = f & 7;
            int sg = slot ^ (row & 7);          // inverse-swizzled global source
            gld_lds16(ga + (size_t)row * K + sg * 8, la + f * 8);
            gld_lds16(gb + (size_t)row * K + sg * 8, lb + f * 8);
        }
    };

    auto compute = [&](int buf) {
        const u16* la = As[buf];
        const u16* lb = Bs[buf];
        bf16x8 af[4][2];
        #pragma unroll
        for (int mi = 0; mi < 4; ++mi) {
            int row = wrr + mi * 16 + lr;
            int base = row * 64;
            af[mi][0] = *reinterpret_cast<const bf16x8*>(la + base + ((0 + lg) ^ (row & 7)) * 8);
            af[mi][1] = *reinterpret_cast<const bf16x8*>(la + base + ((4 + lg) ^ (row & 7)) * 8);
        }
        #pragma unroll
        for (int ni = 0; ni < 4; ++ni) {
            int row = wcc + ni * 16 + lr;
            int base = row * 64;
            bf16x8 b0 = *reinterpret_cast<const bf16x8*>(lb + base + ((0 + lg) ^ (row & 7)) * 8);
            bf16x8 b1 = *reinterpret_cast<const bf16x8*>(lb + base + ((4 + lg) ^ (row & 7)) * 8);
            #pragma unroll
            for (int mi = 0; mi < 4; ++mi) {
                acc[mi][ni] = mfma16(af[mi][0], b0, acc[mi][ni]);
                acc[mi][ni] = mfma16(af[mi][1], b1, acc[mi][ni]);
            }
        }
    };

    stage(0, 0);
    __syncthreads();
    for (int kt = 0; kt < NT; ++kt) {
        if (kt + 1 < NT) stage((kt + 1) & 1, kt + 1);
        compute(kt & 1);
        __syncthreads();
    }

    // epilogue
    #pragma unroll
    for (int mi = 0; mi < 4; ++mi) {
        int r0 = brow + wrr + mi * 16 + lg * 4;
        #pragma unroll
        for (int ni = 0; ni < 4; ++ni) {
            int c = bcol + wcc + ni * 16 + lr;
            float bv = bias[c];
            #pragma unroll
            for (int j = 0; j < 4; ++j) {
                float v = acc[mi][ni][j] + bv;
                size_t idx = (size_t)(r0 + j) * N + c;
                if constexpr (EPI == EPI_GELU) {
                    v = 0.5f * v * (1.0f + erff(v * 0.70710678118f));
                    outb[idx] = f2bf(v);
                } else if constexpr (EPI == EPI_RESF32) {
                    outf[idx] = v + res[idx];
                } else {
                    outb[idx] = f2bf(v);
                }
            }
        }
    }
}

// ---------- causal flash attention v2 ----------
// 4 waves/block, QBLK=128 (32 q-rows per wave), KVBLK=64.
// K staged via global_load_lds (swizzled), V transposed into padded LDS,
// P bounced through per-wave padded LDS. Online softmax in f32.
#define QBLK  128
#define KVBLK 64

__global__ __launch_bounds__(256, 2) void attn2(
    const u16* __restrict__ QKV, u16* __restrict__ O)
{
    __shared__ u16 Ks[64 * 64];       // swizzled, 8 KB
    __shared__ u16 Vt[64 * 72];       // [d][kv], padded stride 72
    __shared__ u16 Pl[4][32 * 72];    // per-wave P, padded stride 72

    const int bx = (gridDim.x - 1) - blockIdx.x;   // heavy-first
    const int bh = blockIdx.y;
    const int b = bh >> 4, h = bh & 15;
    const int q0 = bx * QBLK;
    const int t = threadIdx.x;
    const int lane = t & 63, w = t >> 6;
    const int lr = lane & 15, lg = lane >> 4;

    const size_t rowbase = (size_t)b * SEQ;
    const u16* Qg = QKV + rowbase * QKVS + h * HD;
    const u16* Kg = Qg + 1024;
    const u16* Vg = Qg + 2048;

    // Q fragments: wave w owns rows q0 + w*32 + {0..31}
    bf16x8 qf[2][2];
    #pragma unroll
    for (int mi = 0; mi < 2; ++mi) {
        const u16* qp = Qg + (size_t)(q0 + w * 32 + mi * 16 + lr) * QKVS;
        qf[mi][0] = ldg8(qp + lg * 8);
        qf[mi][1] = ldg8(qp + 32 + lg * 8);
    }

    f32x4 o[2][4] = {};
    float mrow[2][4], lrow[2][4];
    #pragma unroll
    for (int mi = 0; mi < 2; ++mi)
        #pragma unroll
        for (int j = 0; j < 4; ++j) { mrow[mi][j] = -1e30f; lrow[mi][j] = 0.f; }

    const int ntiles = q0 / KVBLK + 2;
    const int qmin_w = q0 + w * 32;
    const int qmax_w = qmin_w + 31;
    u16* Pw = Pl[w];

    for (int tt = 0; tt < ntiles; ++tt) {
        const int kv0 = tt * KVBLK;
        __syncthreads();   // previous tile's reads complete before restage
        // stage K tile [64 kv][64 d], swizzled
        #pragma unroll
        for (int c = 0; c < 2; ++c) {
            int f = c * 256 + t;
            int row = f >> 3, slot = f & 7;
            int sg = slot ^ (row & 7);
            gld_lds16(Kg + (size_t)(kv0 + row) * QKVS + sg * 8, Ks + f * 8);
        }
        // stage V transposed: Vt[d][kv]
        {
            int kv = t & 63, dc = t >> 6;
            const u16* vp = Vg + (size_t)(kv0 + kv) * QKVS + dc * 16;
            bf16x8 v0 = ldg8(vp), v1 = ldg8(vp + 8);
            #pragma unroll
            for (int i2 = 0; i2 < 8; ++i2) {
                Vt[(dc * 16 + i2) * 72 + kv]     = ((const u16*)&v0)[i2];
                Vt[(dc * 16 + 8 + i2) * 72 + kv] = ((const u16*)&v1)[i2];
            }
        }
        __syncthreads();

        if (kv0 <= qmax_w) {
            // QK^T: s[mi][ni], q = q0+w*32+mi*16+(lg*4+j), kv = kv0+ni*16+lr
            f32x4 s[2][4] = {};
            #pragma unroll
            for (int ni = 0; ni < 4; ++ni) {
                int row = ni * 16 + lr;
                int base = row * 64;
                bf16x8 k0 = *reinterpret_cast<const bf16x8*>(Ks + base + ((0 + lg) ^ (row & 7)) * 8);
                bf16x8 k1 = *reinterpret_cast<const bf16x8*>(Ks + base + ((4 + lg) ^ (row & 7)) * 8);
                #pragma unroll
                for (int mi = 0; mi < 2; ++mi) {
                    s[mi][ni] = mfma16(qf[mi][0], k0, s[mi][ni]);
                    s[mi][ni] = mfma16(qf[mi][1], k1, s[mi][ni]);
                }
            }
            // online softmax
            const bool full = (kv0 + KVBLK - 1) <= qmin_w;   // no masking needed
            #pragma unroll
            for (int mi = 0; mi < 2; ++mi) {
                #pragma unroll
                for (int j = 0; j < 4; ++j) {
                    int qi = q0 + w * 32 + mi * 16 + lg * 4 + j;
                    float a0 = s[mi][0][j] * 0.125f;
                    float a1 = s[mi][1][j] * 0.125f;
                    float a2 = s[mi][2][j] * 0.125f;
                    float a3 = s[mi][3][j] * 0.125f;
                    if (!full) {
                        if (kv0 + lr > qi)      a0 = -1e9f;
                        if (kv0 + 16 + lr > qi) a1 = -1e9f;
                        if (kv0 + 32 + lr > qi) a2 = -1e9f;
                        if (kv0 + 48 + lr > qi) a3 = -1e9f;
                    }
                    float mm = fmaxf(fmaxf(a0, a1), fmaxf(a2, a3));
                    mm = fmaxf(mm, __shfl_xor(mm, 1));
                    mm = fmaxf(mm, __shfl_xor(mm, 2));
                    mm = fmaxf(mm, __shfl_xor(mm, 4));
                    mm = fmaxf(mm, __shfl_xor(mm, 8));
                    float mo = mrow[mi][j];
                    float mn = fmaxf(mo, mm);
                    float corr = __expf(mo - mn);
                    mrow[mi][j] = mn;
                    float p0 = __expf(a0 - mn), p1 = __expf(a1 - mn);
                    float p2 = __expf(a2 - mn), p3 = __expf(a3 - mn);
                    float pp = (p0 + p1) + (p2 + p3);
                    pp += __shfl_xor(pp, 1);
                    pp += __shfl_xor(pp, 2);
                    pp += __shfl_xor(pp, 4);
                    pp += __shfl_xor(pp, 8);
                    lrow[mi][j] = lrow[mi][j] * corr + pp;
                    #pragma unroll
                    for (int ni = 0; ni < 4; ++ni) o[mi][ni][j] *= corr;
                    int qr = (mi * 16 + lg * 4 + j) * 72;
                    Pw[qr + lr]      = f2bf(p0);
                    Pw[qr + 16 + lr] = f2bf(p1);
                    Pw[qr + 32 + lr] = f2bf(p2);
                    Pw[qr + 48 + lr] = f2bf(p3);
                }
            }
            // PV: o[mi][ni] += P[32x64] @ V[64x64]
            bf16x8 pa[2][2];
            #pragma unroll
            for (int mi = 0; mi < 2; ++mi) {
                pa[mi][0] = *reinterpret_cast<const bf16x8*>(Pw + (mi * 16 + lr) * 72 + lg * 8);
                pa[mi][1] = *reinterpret_cast<const bf16x8*>(Pw + (mi * 16 + lr) * 72 + 32 + lg * 8);
            }
            #pragma unroll
            for (int ni = 0; ni < 4; ++ni) {
                bf16x8 vb0 = *reinterpret_cast<const bf16x8*>(Vt + (ni * 16 + lr) * 72 + lg * 8);
                bf16x8 vb1 = *reinterpret_cast<const bf16x8*>(Vt + (ni * 16 + lr) * 72 + 32 + lg * 8);
                #pragma unroll
                for (int mi = 0; mi < 2; ++mi) {
                    o[mi][ni] = mfma16(pa[mi][0], vb0, o[mi][ni]);
                    o[mi][ni] = mfma16(pa[mi][1], vb1, o[mi][ni]);
                }
            }
        }
    }

    // normalize + store: O[row][h*64 + d]
    u16* Ob = O + (rowbase + q0 + w * 32) * D_MODEL + h * HD;
    #pragma unroll
    for (int mi = 0; mi < 2; ++mi) {
        #pragma unroll
        for (int j = 0; j < 4; ++j) {
            float inv = 1.0f / lrow[mi][j];
            int r = (mi * 16 + lg * 4 + j) * D_MODEL;
            #pragma unroll
            for (int ni = 0; ni < 4; ++ni)
                Ob[r + ni * 16 + lr] = f2bf(o[mi][ni][j] * inv);
        }
    }
}

// ---------- launch ----------
extern "C" void kernel_launch(void* const* d_in, const int* in_sizes, int n_in,
                              void* d_out, int out_size, void* d_ws, size_t ws_size,
                              hipStream_t stream)
{
    (void)in_sizes; (void)n_in; (void)out_size; (void)ws_size;
    const float* x   = (const float*)d_in[0];
    const float* Wq  = (const float*)d_in[2];
    const float* bq  = (const float*)d_in[3];
    const float* Wk  = (const float*)d_in[4];
    const float* bk  = (const float*)d_in[5];
    const float* Wv  = (const float*)d_in[6];
    const float* bv  = (const float*)d_in[7];
    const float* Wo  = (const float*)d_in[8];
    const float* bo  = (const float*)d_in[9];
    const float* g1  = (const float*)d_in[10];
    const float* be1 = (const float*)d_in[11];
    const float* g2  = (const float*)d_in[12];
    const float* be2 = (const float*)d_in[13];
    const float* W1  = (const float*)d_in[14];
    const float* b1  = (const float*)d_in[15];
    const float* W2  = (const float*)d_in[16];
    const float* b2  = (const float*)d_in[17];
    float* out = (float*)d_out;

    const size_t MM = 1 << 20;   // 1M elems
    u16* Wqkv_b = (u16*)d_ws;            // 3M u16 (Wq,Wk,Wv packed [3072][1024])
    u16* Wo_b = Wqkv_b + 3 * MM;
    u16* W1_b = Wo_b + MM;               // 4M
    u16* W2_b = W1_b + 4 * MM;           // 4M
    u16* hbuf = W2_b + 4 * MM;           // 4M
    u16* QKVb = hbuf + 4 * MM;           // 12M  [4096][3072]
    u16* ctx  = QKVb + 12 * MM;          // 4M
    u16* ffn1 = ctx + 4 * MM;            // 16M
    float* x2 = (float*)(ffn1 + 16 * MM);        // 4M f32
    float* bqkv = (float*)(x2 + 4 * MM);         // 3072 f32

    // weight converts (Wq/Wk/Wv land contiguous -> packed [3072][1024])
    cvt_bf16<<<MM / 1024, 256, 0, stream>>>(Wq, Wqkv_b, MM);
    cvt_bf16<<<MM / 1024, 256, 0, stream>>>(Wk, Wqkv_b + MM, MM);
    cvt_bf16<<<MM / 1024, 256, 0, stream>>>(Wv, Wqkv_b + 2 * MM, MM);
    cvt_bf16<<<MM / 1024, 256, 0, stream>>>(Wo, Wo_b, MM);
    cvt_bf16<<<4 * MM / 1024, 256, 0, stream>>>(W1, W1_b, 4 * MM);
    cvt_bf16<<<4 * MM / 1024, 256, 0, stream>>>(W2, W2_b, 4 * MM);

    // pack QKV bias
    hipMemcpyAsync(bqkv,        bq, D_MODEL * sizeof(float), hipMemcpyDeviceToDevice, stream);
    hipMemcpyAsync(bqkv + 1024, bk, D_MODEL * sizeof(float), hipMemcpyDeviceToDevice, stream);
    hipMemcpyAsync(bqkv + 2048, bv, D_MODEL * sizeof(float), hipMemcpyDeviceToDevice, stream);

    // LN1
    ln_bf16<<<ROWS, 256, 0, stream>>>(x, g1, be1, hbuf);

    dim3 blk(256);
    // fused QKV projection: [4096,1024] @ [3072,1024]^T
    dim3 gqkv(QKVS / 128, ROWS / 128);        // (24, 32)
    gemm_bt<EPI_BF16><<<gqkv, blk, 0, stream>>>(hbuf, Wqkv_b, bqkv, nullptr, QKVb, nullptr, ROWS, QKVS, D_MODEL);

    // attention
    dim3 ga(SEQ / QBLK, BATCH * NH);          // (16, 32)
    attn2<<<ga, blk, 0, stream>>>(QKVb, ctx);

    dim3 gq(D_MODEL / 128, ROWS / 128);       // (8, 32)
    gemm_bt<EPI_RESF32><<<gq, blk, 0, stream>>>(ctx, Wo_b, bo, x, nullptr, x2, ROWS, D_MODEL, D_MODEL);

    // LN2
    ln_bf16<<<ROWS, 256, 0, stream>>>(x2, g2, be2, hbuf);

    dim3 gf1(D_FF / 128, ROWS / 128);         // (32, 32)
    gemm_bt<EPI_GELU><<<gf1, blk, 0, stream>>>(hbuf, W1_b, b1, nullptr, ffn1, nullptr, ROWS, D_FF, D_MODEL);

    gemm_bt<EPI_RESF32><<<gq, blk, 0, stream>>>(ffn1, W2_b, b2, x2, nullptr, out, ROWS, D_MODEL, D_FF);
}